// Round 1
// baseline (44.662 us; speedup 1.0000x reference)
//
#include <hip/hip_runtime.h>

#define T_DIM 1024
#define B_DIM 32
#define C_DIM 512

// Kernel A: means[b*T + j] = mean over C of video[j*B*C + b*C + :]
// One wave (64 lanes) per row; 4 waves per block.
__global__ __launch_bounds__(256) void k_means(const float* __restrict__ video,
                                               float* __restrict__ means) {
    int wave = threadIdx.x >> 6;
    int lane = threadIdx.x & 63;
    int row  = blockIdx.x * 4 + wave;              // row in [0, T*B)
    const float* base = video + (size_t)row * C_DIM;
    float4 a = *(const float4*)(base + lane * 4);
    float4 b = *(const float4*)(base + 256 + lane * 4);
    float s = a.x + a.y + a.z + a.w + b.x + b.y + b.z + b.w;
    #pragma unroll
    for (int off = 32; off; off >>= 1) s += __shfl_xor(s, off);
    if (lane == 0) {
        int bb = row & (B_DIM - 1);                // b = row % 32
        int j  = row >> 5;                         // j = row / 32
        means[bb * T_DIM + j] = s * (1.0f / C_DIM);
    }
}

// Kernel B: one block per batch. Compact labeled means into vm[] via block
// scan, then scale[b][p] = prod_{m=lo..hi} vm[m],
// lo = max(0, p-T+t), hi = min(p, t-1). Stored as scale_s[p*B + b].
__global__ __launch_bounds__(256) void k_scale(const float* __restrict__ means,
                                               const int* __restrict__ labels,
                                               float* __restrict__ scale_s) {
    int b    = blockIdx.x;
    int tid  = threadIdx.x;
    int lane = tid & 63;
    int wave = tid >> 6;
    __shared__ float vm[T_DIM];
    __shared__ int waveTot[4];

    int p0 = tid * 4;
    int4 lv = *(const int4*)(labels + b * T_DIM + p0);
    int f0 = (lv.x == 1), f1 = (lv.y == 1), f2 = (lv.z == 1), f3 = (lv.w == 1);
    int cnt = f0 + f1 + f2 + f3;

    // wave-level inclusive scan of cnt (64 lanes)
    int incl = cnt;
    #pragma unroll
    for (int off = 1; off < 64; off <<= 1) {
        int n = __shfl_up(incl, off);
        if (lane >= off) incl += n;
    }
    if (lane == 63) waveTot[wave] = incl;
    __syncthreads();

    int waveOff = 0;
    for (int w = 0; w < wave; ++w) waveOff += waveTot[w];
    int t = waveTot[0] + waveTot[1] + waveTot[2] + waveTot[3];
    int r = waveOff + incl - cnt;                  // exclusive prefix (rank)

    const float* mb = means + b * T_DIM;
    if (f0) vm[r++] = mb[p0 + 0];
    if (f1) vm[r++] = mb[p0 + 1];
    if (f2) vm[r++] = mb[p0 + 2];
    if (f3) vm[r++] = mb[p0 + 3];
    __syncthreads();

    #pragma unroll
    for (int k = 0; k < 4; ++k) {
        int p  = p0 + k;
        int lo = p - (T_DIM - t); if (lo < 0) lo = 0;
        int hi = p < (t - 1) ? p : (t - 1);
        float s = 1.0f;
        for (int m = lo; m <= hi; ++m) s *= vm[m];
        scale_s[p * B_DIM + b] = s;
    }
}

// Kernel C: out[p,b,c] = audio[p,b,c] * scale_s[p*B+b]; flat elem e>>9 = p*B+b.
__global__ __launch_bounds__(256) void k_apply(const float* __restrict__ audio,
                                               const float* __restrict__ scale_s,
                                               float* __restrict__ out) {
    const int total4 = T_DIM * B_DIM * C_DIM / 4;
    int stride = gridDim.x * blockDim.x;
    for (int i = blockIdx.x * blockDim.x + threadIdx.x; i < total4; i += stride) {
        float s  = scale_s[i >> 7];                // (C/4)=128 float4 per (p,b)
        float4 a = ((const float4*)audio)[i];
        float4 o = make_float4(a.x * s, a.y * s, a.z * s, a.w * s);
        ((float4*)out)[i] = o;
    }
}

extern "C" void kernel_launch(void* const* d_in, const int* in_sizes, int n_in,
                              void* d_out, int out_size, void* d_ws, size_t ws_size,
                              hipStream_t stream) {
    const float* video  = (const float*)d_in[0];
    const float* audio  = (const float*)d_in[1];
    const int*   labels = (const int*)d_in[2];
    float* out     = (float*)d_out;
    float* means   = (float*)d_ws;                 // B*T floats = 128 KB
    float* scale_s = means + B_DIM * T_DIM;        // T*B floats = 128 KB

    k_means<<<(T_DIM * B_DIM) / 4, 256, 0, stream>>>(video, means);
    k_scale<<<B_DIM, 256, 0, stream>>>(means, labels, scale_s);
    k_apply<<<2048, 256, 0, stream>>>(audio, scale_s, out);
}

// Round 2
// 38.672 us; speedup vs baseline: 1.1549x; 1.1549x over previous
//
#include <hip/hip_runtime.h>

#define T_DIM 1024
#define B_DIM 32
#define C_DIM 512

// Fused kernel: one block per batch.
// 1) Block-scan compaction of labeled positions p (labels[b][p]==1) -> pos[0..t)
// 2) Each wave mean-reduces video rows (pos[r], b) for r = wave, wave+4, ...
//    (row = 2 KB, lanes load 2x float4 = coalesced)
// 3) scale[b][p] = prod_{m=lo..hi} vm[m], lo = max(0,p-T+t), hi = min(p,t-1)
__global__ __launch_bounds__(256) void k_scale_fused(const float* __restrict__ video,
                                                     const int* __restrict__ labels,
                                                     float* __restrict__ scale_s) {
    int b    = blockIdx.x;
    int tid  = threadIdx.x;
    int lane = tid & 63;
    int wave = tid >> 6;
    __shared__ float vm[T_DIM];
    __shared__ int   pos[T_DIM];
    __shared__ int   waveTot[4];

    int p0 = tid * 4;
    int4 lv = *(const int4*)(labels + b * T_DIM + p0);
    int f0 = (lv.x == 1), f1 = (lv.y == 1), f2 = (lv.z == 1), f3 = (lv.w == 1);
    int cnt = f0 + f1 + f2 + f3;

    // wave-level inclusive scan of cnt (64 lanes)
    int incl = cnt;
    #pragma unroll
    for (int off = 1; off < 64; off <<= 1) {
        int n = __shfl_up(incl, off);
        if (lane >= off) incl += n;
    }
    if (lane == 63) waveTot[wave] = incl;
    __syncthreads();

    int waveOff = 0;
    for (int w = 0; w < wave; ++w) waveOff += waveTot[w];
    int t = waveTot[0] + waveTot[1] + waveTot[2] + waveTot[3];
    int r = waveOff + incl - cnt;                  // exclusive prefix (rank)

    if (f0) pos[r++] = p0 + 0;
    if (f1) pos[r++] = p0 + 1;
    if (f2) pos[r++] = p0 + 2;
    if (f3) pos[r++] = p0 + 3;
    __syncthreads();

    // mean-reduce only the labeled rows
    for (int rr = wave; rr < t; rr += 4) {
        const float* src = video + (size_t)pos[rr] * (B_DIM * C_DIM) + b * C_DIM;
        float4 a  = *(const float4*)(src + lane * 4);
        float4 b4 = *(const float4*)(src + 256 + lane * 4);
        float s = a.x + a.y + a.z + a.w + b4.x + b4.y + b4.z + b4.w;
        #pragma unroll
        for (int off = 32; off; off >>= 1) s += __shfl_xor(s, off);
        if (lane == 0) vm[rr] = s * (1.0f / C_DIM);
    }
    __syncthreads();

    #pragma unroll
    for (int k = 0; k < 4; ++k) {
        int p  = p0 + k;
        int lo = p - (T_DIM - t); if (lo < 0) lo = 0;
        int hi = p < (t - 1) ? p : (t - 1);
        float s = 1.0f;
        for (int m = lo; m <= hi; ++m) s *= vm[m];
        scale_s[p * B_DIM + b] = s;
    }
}

// out[p,b,c] = audio[p,b,c] * scale_s[p*B+b]; flat float4 index i>>7 = p*B+b.
__global__ __launch_bounds__(256) void k_apply(const float* __restrict__ audio,
                                               const float* __restrict__ scale_s,
                                               float* __restrict__ out) {
    const int total4 = T_DIM * B_DIM * C_DIM / 4;
    int stride = gridDim.x * blockDim.x;
    for (int i = blockIdx.x * blockDim.x + threadIdx.x; i < total4; i += stride) {
        float s  = scale_s[i >> 7];                // (C/4)=128 float4 per (p,b)
        float4 a = ((const float4*)audio)[i];
        float4 o = make_float4(a.x * s, a.y * s, a.z * s, a.w * s);
        ((float4*)out)[i] = o;
    }
}

extern "C" void kernel_launch(void* const* d_in, const int* in_sizes, int n_in,
                              void* d_out, int out_size, void* d_ws, size_t ws_size,
                              hipStream_t stream) {
    const float* video  = (const float*)d_in[0];
    const float* audio  = (const float*)d_in[1];
    const int*   labels = (const int*)d_in[2];
    float* out     = (float*)d_out;
    float* scale_s = (float*)d_ws;                 // T*B floats = 128 KB

    k_scale_fused<<<B_DIM, 256, 0, stream>>>(video, labels, scale_s);
    k_apply<<<2048, 256, 0, stream>>>(audio, scale_s, out);
}

// Round 4
// 34.841 us; speedup vs baseline: 1.2819x; 1.1100x over previous
//
#include <hip/hip_runtime.h>

#define T_DIM 1024
#define B_DIM 32
#define C_DIM 512
#define PROWS 16   // p-rows per block

typedef float f32x4 __attribute__((ext_vector_type(4)));

// One block = one batch b, 16 consecutive p-rows.
// Phase A (redundant per block, L2-served): block-scan compaction of labeled
// positions, mean-reduce labeled video rows, windowed product -> sscale[16].
// Phase B: stream audio*scale -> out with nontemporal float4.
__global__ __launch_bounds__(256) void k_fused(const float* __restrict__ video,
                                               const float* __restrict__ audio,
                                               const int* __restrict__ labels,
                                               float* __restrict__ out) {
    int b     = blockIdx.y;
    int pBase = blockIdx.x * PROWS;
    int tid   = threadIdx.x;
    int lane  = tid & 63;
    int wave  = tid >> 6;
    __shared__ float vm[T_DIM];
    __shared__ int   pos[T_DIM];
    __shared__ int   waveTot[4];
    __shared__ float sscale[PROWS];

    // ---- label scan / compaction ----
    int p0 = tid * 4;
    int4 lv = *(const int4*)(labels + b * T_DIM + p0);
    int f0 = (lv.x == 1), f1 = (lv.y == 1), f2 = (lv.z == 1), f3 = (lv.w == 1);
    int cnt = f0 + f1 + f2 + f3;

    int incl = cnt;
    #pragma unroll
    for (int off = 1; off < 64; off <<= 1) {
        int n = __shfl_up(incl, off);
        if (lane >= off) incl += n;
    }
    if (lane == 63) waveTot[wave] = incl;
    __syncthreads();

    int waveOff = 0;
    for (int w = 0; w < wave; ++w) waveOff += waveTot[w];
    int t = waveTot[0] + waveTot[1] + waveTot[2] + waveTot[3];
    int r = waveOff + incl - cnt;

    if (f0) pos[r++] = p0 + 0;
    if (f1) pos[r++] = p0 + 1;
    if (f2) pos[r++] = p0 + 2;
    if (f3) pos[r++] = p0 + 3;
    __syncthreads();

    // ---- means of labeled rows (each row 2 KB, L2-hit after first block) ----
    for (int rr = wave; rr < t; rr += 4) {
        const float* src = video + (size_t)pos[rr] * (B_DIM * C_DIM) + b * C_DIM;
        float4 a  = *(const float4*)(src + lane * 4);
        float4 b4 = *(const float4*)(src + 256 + lane * 4);
        float s = a.x + a.y + a.z + a.w + b4.x + b4.y + b4.z + b4.w;
        #pragma unroll
        for (int off = 32; off; off >>= 1) s += __shfl_xor(s, off);
        if (lane == 0) vm[rr] = s * (1.0f / C_DIM);
    }
    __syncthreads();

    // ---- windowed products for this block's 16 rows ----
    if (tid < PROWS) {
        int p  = pBase + tid;
        int lo = p - (T_DIM - t); if (lo < 0) lo = 0;
        int hi = p < (t - 1) ? p : (t - 1);
        float s = 1.0f;
        for (int m = lo; m <= hi; ++m) s *= vm[m];
        sscale[tid] = s;
    }
    __syncthreads();

    // ---- stream: out[p,b,:] = audio[p,b,:] * sscale ----
    // float4 row base for (p,b) = (p*B + b) * 128; two rows per iteration.
    int half = tid >> 7;           // 0..1
    int c4   = tid & 127;          // float4 index within row
    #pragma unroll
    for (int i = 0; i < PROWS / 2; ++i) {
        int k = i * 2 + half;
        size_t base = ((size_t)(pBase + k) * B_DIM + b) * (C_DIM / 4) + c4;
        float s  = sscale[k];
        f32x4 a = __builtin_nontemporal_load((const f32x4*)audio + base);
        f32x4 o = a * s;
        __builtin_nontemporal_store(o, (f32x4*)out + base);
    }
}

extern "C" void kernel_launch(void* const* d_in, const int* in_sizes, int n_in,
                              void* d_out, int out_size, void* d_ws, size_t ws_size,
                              hipStream_t stream) {
    const float* video  = (const float*)d_in[0];
    const float* audio  = (const float*)d_in[1];
    const int*   labels = (const int*)d_in[2];
    float* out = (float*)d_out;

    dim3 grid(T_DIM / PROWS, B_DIM);
    k_fused<<<grid, 256, 0, stream>>>(video, audio, labels, out);
}

// Round 5
// 30.402 us; speedup vs baseline: 1.4691x; 1.1460x over previous
//
#include <hip/hip_runtime.h>

#define T_DIM 1024
#define B_DIM 32
#define C_DIM 512
#define PROWS 16   // p-rows per block

typedef float f32x4 __attribute__((ext_vector_type(4)));

// One block = one batch b, 16 consecutive p-rows.
// Preamble (scan -> means -> windowed product) finishes BEFORE audio issue;
// the 8 audio loads then stay in flight with no intervening barrier.
__global__ __launch_bounds__(256) void k_fused(const float* __restrict__ video,
                                               const float* __restrict__ audio,
                                               const int* __restrict__ labels,
                                               float* __restrict__ out) {
    int b     = blockIdx.y;
    int pBase = blockIdx.x * PROWS;
    int tid   = threadIdx.x;
    int lane  = tid & 63;
    int wave  = tid >> 6;
    __shared__ float vm[T_DIM];
    __shared__ int   pos[T_DIM];
    __shared__ int   waveTot[4];
    __shared__ float sscale[PROWS];

    // ---- label scan / compaction ----
    int p0 = tid * 4;
    int4 lv = *(const int4*)(labels + b * T_DIM + p0);
    int f0 = (lv.x == 1), f1 = (lv.y == 1), f2 = (lv.z == 1), f3 = (lv.w == 1);
    int cnt = f0 + f1 + f2 + f3;

    int incl = cnt;
    #pragma unroll
    for (int off = 1; off < 64; off <<= 1) {
        int n = __shfl_up(incl, off);
        if (lane >= off) incl += n;
    }
    if (lane == 63) waveTot[wave] = incl;
    __syncthreads();

    int waveOff = 0;
    for (int w = 0; w < wave; ++w) waveOff += waveTot[w];
    int t = waveTot[0] + waveTot[1] + waveTot[2] + waveTot[3];
    int r = waveOff + incl - cnt;

    if (f0) pos[r++] = p0 + 0;
    if (f1) pos[r++] = p0 + 1;
    if (f2) pos[r++] = p0 + 2;
    if (f3) pos[r++] = p0 + 3;
    __syncthreads();

    // ---- means of labeled rows, 2 rows per wave-iteration ----
    for (int rr = wave; rr < t; rr += 8) {
        const float* srcA = video + (size_t)pos[rr] * (B_DIM * C_DIM) + b * C_DIM;
        int rr2 = rr + 4;
        bool has2 = rr2 < t;
        const float* srcB = has2 ? video + (size_t)pos[rr2] * (B_DIM * C_DIM) + b * C_DIM
                                 : srcA;
        float4 a0 = *(const float4*)(srcA + lane * 4);
        float4 a1 = *(const float4*)(srcA + 256 + lane * 4);
        float4 b0 = *(const float4*)(srcB + lane * 4);
        float4 b1 = *(const float4*)(srcB + 256 + lane * 4);
        float sA = a0.x + a0.y + a0.z + a0.w + a1.x + a1.y + a1.z + a1.w;
        float sB = b0.x + b0.y + b0.z + b0.w + b1.x + b1.y + b1.z + b1.w;
        #pragma unroll
        for (int off = 32; off; off >>= 1) {
            sA += __shfl_xor(sA, off);
            sB += __shfl_xor(sB, off);
        }
        if (lane == 0) {
            vm[rr] = sA * (1.0f / C_DIM);
            if (has2) vm[rr2] = sB * (1.0f / C_DIM);
        }
    }
    __syncthreads();

    // ---- windowed products (16 threads), last barrier BEFORE audio issue ----
    if (tid < PROWS) {
        int p  = pBase + tid;
        int lo = p - (T_DIM - t); if (lo < 0) lo = 0;
        int hi = p < (t - 1) ? p : (t - 1);
        float s = 1.0f;
        for (int m = lo; m <= hi; ++m) s *= vm[m];
        sscale[tid] = s;
    }
    __syncthreads();

    // ---- issue all 8 audio row-loads; no barrier until the stores ----
    int half = tid >> 7;           // 0..1
    int c4   = tid & 127;          // float4 index within row
    const int rstep = 2 * B_DIM * (C_DIM / 4);   // 2 p-rows in float4 units
    int base0 = ((pBase + half) * B_DIM + b) * (C_DIM / 4) + c4;

    f32x4 a[8];
    #pragma unroll
    for (int i = 0; i < 8; ++i)
        a[i] = *((const f32x4*)audio + base0 + i * rstep);

    float sc[8];
    #pragma unroll
    for (int i = 0; i < 8; ++i)
        sc[i] = sscale[i * 2 + half];            // LDS reads overlap loads

    #pragma unroll
    for (int i = 0; i < 8; ++i)
        *((f32x4*)out + base0 + i * rstep) = a[i] * sc[i];
}

extern "C" void kernel_launch(void* const* d_in, const int* in_sizes, int n_in,
                              void* d_out, int out_size, void* d_ws, size_t ws_size,
                              hipStream_t stream) {
    const float* video  = (const float*)d_in[0];
    const float* audio  = (const float*)d_in[1];
    const int*   labels = (const int*)d_in[2];
    float* out = (float*)d_out;

    dim3 grid(T_DIM / PROWS, B_DIM);
    k_fused<<<grid, 256, 0, stream>>>(video, audio, labels, out);
}

// Round 6
// 29.213 us; speedup vs baseline: 1.5289x; 1.0407x over previous
//
#include <hip/hip_runtime.h>

#define T_DIM 1024
#define B_DIM 32
#define C_DIM 512
#define PROWS 16   // p-rows per block

typedef float f32x4 __attribute__((ext_vector_type(4)));

// One block = one batch b, 16 consecutive p-rows. Phases:
//   A: prefetch 2 audio rows + labels; block-scan label compaction
//   B: means of labeled video rows (L2-served, vmcnt queue otherwise empty)
//   C: issue remaining 6 audio rows; windowed product; barrier drains the
//      grid-wide audio read at full concurrency
//   D: mul + store burst
__global__ __launch_bounds__(256) void k_fused(const float* __restrict__ video,
                                               const float* __restrict__ audio,
                                               const int* __restrict__ labels,
                                               float* __restrict__ out) {
    int b     = blockIdx.y;
    int pBase = blockIdx.x * PROWS;
    int tid   = threadIdx.x;
    int lane  = tid & 63;
    int wave  = tid >> 6;
    __shared__ float vm[T_DIM];
    __shared__ int   pos[T_DIM];
    __shared__ int   waveTot[4];
    __shared__ float sscale[PROWS];

    // streaming geometry: thread handles rows k = 2*i + half, i = 0..7
    int half = tid >> 7;
    int c4   = tid & 127;
    const int rstep = 2 * B_DIM * (C_DIM / 4);
    int base0 = ((pBase + half) * B_DIM + b) * (C_DIM / 4) + c4;
    const f32x4* ain  = (const f32x4*)audio;
    f32x4*       aout = (f32x4*)out;

    // ---- phase A: prefetch first 2 audio rows + labels together ----
    f32x4 a0 = ain[base0];
    f32x4 a1 = ain[base0 + rstep];
    int4 lv = *(const int4*)(labels + b * T_DIM + tid * 4);

    int p0 = tid * 4;
    int f0 = (lv.x == 1), f1 = (lv.y == 1), f2 = (lv.z == 1), f3 = (lv.w == 1);
    int cnt = f0 + f1 + f2 + f3;

    int incl = cnt;
    #pragma unroll
    for (int off = 1; off < 64; off <<= 1) {
        int n = __shfl_up(incl, off);
        if (lane >= off) incl += n;
    }
    if (lane == 63) waveTot[wave] = incl;
    __syncthreads();

    int waveOff = 0;
    for (int w = 0; w < wave; ++w) waveOff += waveTot[w];
    int t = waveTot[0] + waveTot[1] + waveTot[2] + waveTot[3];
    int r = waveOff + incl - cnt;

    if (f0) pos[r++] = p0 + 0;
    if (f1) pos[r++] = p0 + 1;
    if (f2) pos[r++] = p0 + 2;
    if (f3) pos[r++] = p0 + 3;
    __syncthreads();

    // ---- phase B: means of labeled rows, 2 rows per wave-iteration ----
    for (int rr = wave; rr < t; rr += 8) {
        const float* srcA = video + (size_t)pos[rr] * (B_DIM * C_DIM) + b * C_DIM;
        int rr2 = rr + 4;
        bool has2 = rr2 < t;
        const float* srcB = has2 ? video + (size_t)pos[rr2] * (B_DIM * C_DIM) + b * C_DIM
                                 : srcA;
        float4 va0 = *(const float4*)(srcA + lane * 4);
        float4 va1 = *(const float4*)(srcA + 256 + lane * 4);
        float4 vb0 = *(const float4*)(srcB + lane * 4);
        float4 vb1 = *(const float4*)(srcB + 256 + lane * 4);
        float sA = va0.x + va0.y + va0.z + va0.w + va1.x + va1.y + va1.z + va1.w;
        float sB = vb0.x + vb0.y + vb0.z + vb0.w + vb1.x + vb1.y + vb1.z + vb1.w;
        #pragma unroll
        for (int off = 32; off; off >>= 1) {
            sA += __shfl_xor(sA, off);
            sB += __shfl_xor(sB, off);
        }
        if (lane == 0) {
            vm[rr] = sA * (1.0f / C_DIM);
            if (has2) vm[rr2] = sB * (1.0f / C_DIM);
        }
    }
    __syncthreads();

    // ---- phase C: issue remaining 6 audio rows, then windowed product ----
    f32x4 a2 = ain[base0 + 2 * rstep];
    f32x4 a3 = ain[base0 + 3 * rstep];
    f32x4 a4 = ain[base0 + 4 * rstep];
    f32x4 a5 = ain[base0 + 5 * rstep];
    f32x4 a6 = ain[base0 + 6 * rstep];
    f32x4 a7 = ain[base0 + 7 * rstep];

    if (tid < PROWS) {
        int p  = pBase + tid;
        int lo = p - (T_DIM - t); if (lo < 0) lo = 0;
        int hi = p < (t - 1) ? p : (t - 1);
        float s = 1.0f;
        for (int m = lo; m <= hi; ++m) s *= vm[m];
        sscale[tid] = s;
    }
    __syncthreads();   // drains the 6 in-flight audio loads grid-wide

    // ---- phase D: mul + store burst ----
    float s0 = sscale[0 + half], s1 = sscale[2 + half];
    float s2 = sscale[4 + half], s3 = sscale[6 + half];
    float s4 = sscale[8 + half], s5 = sscale[10 + half];
    float s6 = sscale[12 + half], s7 = sscale[14 + half];

    aout[base0 + 0 * rstep] = a0 * s0;
    aout[base0 + 1 * rstep] = a1 * s1;
    aout[base0 + 2 * rstep] = a2 * s2;
    aout[base0 + 3 * rstep] = a3 * s3;
    aout[base0 + 4 * rstep] = a4 * s4;
    aout[base0 + 5 * rstep] = a5 * s5;
    aout[base0 + 6 * rstep] = a6 * s6;
    aout[base0 + 7 * rstep] = a7 * s7;
}

extern "C" void kernel_launch(void* const* d_in, const int* in_sizes, int n_in,
                              void* d_out, int out_size, void* d_ws, size_t ws_size,
                              hipStream_t stream) {
    const float* video  = (const float*)d_in[0];
    const float* audio  = (const float*)d_in[1];
    const int*   labels = (const int*)d_in[2];
    float* out = (float*)d_out;

    dim3 grid(T_DIM / PROWS, B_DIM);
    k_fused<<<grid, 256, 0, stream>>>(video, audio, labels, out);
}